// Round 10
// baseline (1771.378 us; speedup 1.0000x reference)
//
#include <hip/hip_runtime.h>

typedef float F2 __attribute__((ext_vector_type(2)));

#define NB 4
#define NC 17
#define T0 75000
#define NH 32
#define NK 8

// ---------------- diff precompute: D[b][c][t] = X[t+1]-X[t], D[T0-1]=0 ----------------
__global__ void diffK(const float* __restrict__ X, float* __restrict__ D) {
    int t = blockIdx.x * 256 + threadIdx.x;
    int row = blockIdx.y;
    if (t < T0) {
        size_t o = (size_t)row * T0 + t;
        D[o] = (t < T0 - 1) ? (X[o + 1] - X[o]) : 0.f;
    }
}

// ---------------- kernel A: di 0..5 (d = 1..32), LDS-tiled, champion scalar body ----------------
constexpr int TS = 1024;
constexpr int A_TILES = 74;
constexpr int A_BLOCKS_PER_G = 128 * A_TILES;   // 9472
constexpr int A_GROUPS = 12;
constexpr int A_TOTAL_BLOCKS = A_GROUPS * A_BLOCKS_PER_G;  // 113664

template <bool USE_D>
__global__ __launch_bounds__(256) void kernA(const float* __restrict__ X,
                                             const float* __restrict__ Dws,
                                             const float* __restrict__ Wt,
                                             const int* __restrict__ idx,
                                             float* __restrict__ out) {
    __shared__ float Sbuf[TS + 8 * 32 + 2];
    __shared__ float red[4][16];

    const int tid = threadIdx.x;
    const int bid = blockIdx.x;
    const int ga = bid / A_BLOCKS_PER_G;
    const int rem = bid - ga * A_BLOCKS_PER_G;
    const int b = rem & 3;                       // XCD locality: b fastest
    const int z = rem >> 2;
    const int h = z & 31;
    const int tile = z >> 5;
    const int di = ga >> 1, diff = ga & 1;
    const int d = 1 << di;
    const int T = T0 - diff;
    const int t0 = tile * TS;
    const int span = TS + 8 * d;
    const int g0 = t0 - 4 * d;                   // even

    const int* ip = idx + (ga * NH + h) * 8;
    int offs[8];
#pragma unroll
    for (int i = 0; i < 8; ++i)
        offs[i] = __builtin_amdgcn_readfirstlane((b * NC + ip[i]) * T0);

    if (USE_D) {
        const float* base = diff ? Dws : X;
        for (int e = tid * 2; e < span; e += 512) {
            int u = g0 + e;
            F2 s = {0.f, 0.f};
            if (u >= 0 && u + 1 < T0) {
#pragma unroll
                for (int i = 0; i < 8; ++i) s += *(const F2*)(base + offs[i] + u);
            } else {
#pragma unroll
                for (int c = 0; c < 2; ++c) {
                    int uc = u + c;
                    float sc = 0.f;
                    if (uc >= 0 && uc < T0) {
#pragma unroll
                        for (int i = 0; i < 8; ++i) sc += base[offs[i] + uc];
                    }
                    s[c] = sc;
                }
            }
            if (e + 1 < span) *(F2*)(Sbuf + e) = s;
            else Sbuf[e] = s.x;
        }
    } else {
        for (int ls = tid; ls < span; ls += 256) {
            int u = g0 + ls;
            float s = 0.f;
            if (diff) {
                if (u >= 0 && u < T0 - 1) {
#pragma unroll
                    for (int i = 0; i < 8; ++i) s += X[offs[i] + u + 1] - X[offs[i] + u];
                }
            } else {
                if (u >= 0 && u < T0) {
#pragma unroll
                    for (int i = 0; i < 8; ++i) s += X[offs[i] + u];
                }
            }
            Sbuf[ls] = s;
        }
    }
    __syncthreads();

    const float* wp = Wt + (ga * (NK * NH) + h * NK) * 9;
    float w[72];
#pragma unroll
    for (int i = 0; i < 72; ++i) w[i] = wp[i];   // block-uniform -> SGPRs

    float accM[8], accC[8];
#pragma unroll
    for (int k = 0; k < 8; ++k) { accM[k] = 0.f; accC[k] = 0.f; }

#pragma unroll
    for (int it = 0; it < 4; ++it) {
        int pos = tid + it * 256;
        int t = t0 + pos;
        if (t < T) {
            float zv[8];
#pragma unroll
            for (int k = 0; k < 8; ++k) zv[k] = 0.f;
#pragma unroll
            for (int j = 0; j < 9; ++j) {
                float g = Sbuf[pos + j * d];
#pragma unroll
                for (int k = 0; k < 8; ++k) zv[k] = fmaf(w[k * 9 + j], g, zv[k]);
            }
            float best = zv[0], worst = zv[0];
            int biK = 0, wiK = 0;
#pragma unroll
            for (int k = 1; k < 8; ++k) {
                if (zv[k] > best)  { best = zv[k];  biK = k; }
                if (zv[k] < worst) { worst = zv[k]; wiK = k; }
            }
#pragma unroll
            for (int k = 0; k < 8; ++k) {
                accM[k] += (k == biK) ? best : 0.f;
                accC[k] += (k == wiK) ? 1.f  : 0.f;
            }
        }
    }

#pragma unroll
    for (int k = 0; k < 8; ++k) {
#pragma unroll
        for (int sh = 1; sh < 64; sh <<= 1) {
            accM[k] += __shfl_xor(accM[k], sh, 64);
            accC[k] += __shfl_xor(accC[k], sh, 64);
        }
    }
    int wv = tid >> 6, lane = tid & 63;
    if (lane == 0) {
#pragma unroll
        for (int k = 0; k < 8; ++k) { red[wv][k] = accM[k]; red[wv][8 + k] = accC[k]; }
    }
    __syncthreads();
    if (tid < 16) {
        float v = red[0][tid] + red[1][tid] + red[2][tid] + red[3][tid];
        int which = tid >> 3;
        int k = tid & 7;
        int o = ga * 2 + which;
        atomicAdd(&out[(size_t)b * 14336 + (o * NH + h) * NK + k], v);
    }
}

// ---------------- kernel P: di 6..13 phase-space LDS tiles ----------------
// position t = r + q*d; y_r[q] = S[r + q*d] -> contiguous 9-tap conv over q.
// Block = (b, h, group, r-tile of 64 phases, q-tile of 16). Tile rows qi=0..23
// hold qglob = qb-4+qi; out-of-range rows stage 0 == reference zero-padding.
constexpr int QT = 16;
constexpr int PROWS = QT + 8;                   // 24

struct PG { int base, rtiles, qtiles, di, diff; };
constexpr PG PGS[16] = {
    {0,      1,  74,  6, 0}, {9472,   1,  74,  6, 1},
    {18944,  2,  37,  7, 0}, {28416,  2,  37,  7, 1},
    {37888,  4,  19,  8, 0}, {47616,  4,  19,  8, 1},
    {57344,  8,  10,  9, 0}, {67584,  8,  10,  9, 1},
    {77824, 16,   5, 10, 0}, {88064, 16,   5, 10, 1},
    {98304, 32,   3, 11, 0}, {110592,32,   3, 11, 1},
    {122880,64,   2, 12, 0}, {139264,64,   2, 12, 1},
    {155648,128,  1, 13, 0}, {172032,128,  1, 13, 1},
};
constexpr int P_BLOCKS = 188416;

__device__ __forceinline__ float packK(float z, int k) {
    unsigned u = (__float_as_uint(z) & 0xFFFFFFF8u) | (unsigned)k;
    return __uint_as_float(u);
}
__device__ __forceinline__ void load_w2(const float* __restrict__ wp, F2* w2) {
#pragma unroll
    for (int j = 0; j < 9; ++j)
#pragma unroll
        for (int kp = 0; kp < 4; ++kp)
            w2[j * 4 + kp] = (F2){wp[(2 * kp) * 9 + j], wp[(2 * kp + 1) * 9 + j]};
}
// z2[kp] = {z_2kp, z_2kp+1} -> best/worst with k packed in low mantissa bits
__device__ __forceinline__ void pkSel(const F2* z2, float& best, float& worst) {
    F2 p[4];
#pragma unroll
    for (int kp = 0; kp < 4; ++kp) {
        p[kp].x = packK(z2[kp].x, 2 * kp);
        p[kp].y = packK(z2[kp].y, 2 * kp + 1);
    }
    F2 ma = __builtin_elementwise_max(p[0], p[1]);
    F2 mb = __builtin_elementwise_max(p[2], p[3]);
    F2 mc = __builtin_elementwise_max(ma, mb);
    best = fmaxf(mc.x, mc.y);
    F2 na = __builtin_elementwise_min(p[0], p[1]);
    F2 nb = __builtin_elementwise_min(p[2], p[3]);
    F2 nc = __builtin_elementwise_min(na, nb);
    worst = fminf(nc.x, nc.y);
}

template <bool USE_D>
__device__ __forceinline__ float gatherF(const float* __restrict__ base,
                                         const int* offs, int u, int T, int diffF) {
    float s = 0.f;
    if (u >= 0 && u < T) {
        if (!USE_D && diffF) {
            F2 acc = {0.f, 0.f};
#pragma unroll
            for (int i = 0; i < 8; ++i) {
                F2 t = {base[offs[i] + u], base[offs[i] + u + 1]};
                acc += t;
            }
            s = acc.y - acc.x;
        } else {
            float a0 = base[offs[0] + u], a1 = base[offs[1] + u];
            float a2 = base[offs[2] + u], a3 = base[offs[3] + u];
            float a4 = base[offs[4] + u], a5 = base[offs[5] + u];
            float a6 = base[offs[6] + u], a7 = base[offs[7] + u];
            s = ((a0 + a1) + (a2 + a3)) + ((a4 + a5) + (a6 + a7));
        }
    }
    return s;
}

template <bool USE_D>
__global__ __launch_bounds__(256, 4) void kernP(const float* __restrict__ X,
                                                const float* __restrict__ Dws,
                                                const float* __restrict__ Wt,
                                                const int* __restrict__ idx,
                                                float* __restrict__ out) {
    __shared__ __align__(16) float smem[4096];  // [0,2048)=maxb, [2048,..)=Sld(1536)/minb(2048)
    float* maxb = smem;
    float* Sld  = smem + 2048;

    const int tid = threadIdx.x;
    const int bid = blockIdx.x;

    int di = 6, diff = 0, beta = 0, lrt = 0;
#pragma unroll
    for (int g = 0; g < 16; ++g) {
        const int sz = 128 * PGS[g].rtiles * PGS[g].qtiles;
        if (bid >= PGS[g].base && bid < PGS[g].base + sz) {
            beta = bid - PGS[g].base;
            di = PGS[g].di; diff = PGS[g].diff; lrt = PGS[g].di - 6;  // log2(rtiles)
        }
    }
    const int b = beta & 3;                      // XCD locality
    const int z = beta >> 2;
    const int h = z & 31;
    const int rq = z >> 5;
    const int rtile = rq & ((1 << lrt) - 1);
    const int qtile = rq >> lrt;

    const int d = 1 << di;
    const int T = T0 - diff;
    const int ga = di * 2 + diff;
    const int r0 = rtile * 64;
    const int qb = qtile * QT;

    const int* ip = idx + (ga * NH + h) * 8;
    int offs[8];
#pragma unroll
    for (int i = 0; i < 8; ++i)
        offs[i] = __builtin_amdgcn_readfirstlane((b * NC + ip[i]) * T0);

    F2 w2[36];
    load_w2(Wt + (ga * (NK * NH) + h * NK) * 9, w2);

    const float* base = (USE_D && diff) ? Dws : X;

#pragma unroll
    for (int k = 0; k < 8; ++k) maxb[(k << 8) + tid] = 0.f;

    // stage 24x64 phase tile: row qi (qglob = qb-4+qi), col ln (r = r0+ln)
    // element e = qi*64+ln ; t = r0+ln + (qb-4+qi)*d ; 6 gathers/thread, dense burst
#pragma unroll
    for (int it = 0; it < 6; ++it) {
        const int e = tid + it * 256;
        const int qi = e >> 6, ln = e & 63;
        const int t = r0 + ln + (qb - 4 + qi) * d;
        Sld[e] = gatherF<USE_D>(base, offs, t, T, diff);
    }
    __syncthreads();

    const int r = tid & 63;
    const int qs = tid >> 6;                     // 4 waves over q
    float* binsM = maxb + tid;
    unsigned cnt = 0;                            // 8 x 4-bit fields (<=4 per k)

#pragma unroll
    for (int it = 0; it < 4; ++it) {
        const int qloc = qs + it * 4;            // 0..15
        const int t = r0 + r + (qb + qloc) * d;
        if (t < T) {                             // wave-uniform-ish: execz-skips dead rows
            F2 z2[4];
#pragma unroll
            for (int kp = 0; kp < 4; ++kp) z2[kp] = (F2){0.f, 0.f};
#pragma unroll
            for (int j = 0; j < 9; ++j) {
                float g = Sld[(qloc + j) * 64 + r];
                F2 g2 = {g, g};
#pragma unroll
                for (int kp = 0; kp < 4; ++kp)
                    z2[kp] = __builtin_elementwise_fma(w2[j * 4 + kp], g2, z2[kp]);
            }
            float best, worst;
            pkSel(z2, best, worst);
            atomicAdd(&binsM[(__float_as_uint(best) & 7) << 8], best);
            cnt += 1u << ((__float_as_uint(worst) & 7) << 2);
        }
    }

    __syncthreads();                             // Sld reads done; overlay minb
    float* minb = smem + 2048;
#pragma unroll
    for (int k = 0; k < 8; ++k)
        minb[(k << 8) + tid] = (float)((cnt >> (k * 4)) & 15u);

    __syncthreads();
    int bin = tid >> 4, i0 = tid & 15;
    const float* src = (bin < 8) ? (maxb + (bin << 8)) : (minb + ((bin - 8) << 8));
    float v = 0.f;
#pragma unroll
    for (int j = 0; j < 16; ++j) v += src[i0 + (j << 4)];
    v += __shfl_xor(v, 1, 64);
    v += __shfl_xor(v, 2, 64);
    v += __shfl_xor(v, 4, 64);
    v += __shfl_xor(v, 8, 64);
    if (i0 == 0) {
        int k = bin & 7;
        int o = ga * 2 + (bin >> 3);
        atomicAdd(&out[(size_t)b * 14336 + (o * NH + h) * NK + k], v);
    }
}

__global__ void zeroK(float* __restrict__ out, int n) {
    int i = blockIdx.x * 256 + threadIdx.x;
    if (i < n) out[i] = 0.f;
}

extern "C" void kernel_launch(void* const* d_in, const int* in_sizes, int n_in,
                              void* d_out, int out_size, void* d_ws, size_t ws_size,
                              hipStream_t stream) {
    const float* X  = (const float*)d_in[0];
    const float* Wt = (const float*)d_in[1];
    const int*  idx = (const int*)d_in[2];
    float* out = (float*)d_out;
    float* Dws = (float*)d_ws;

    const size_t D_BYTES = (size_t)NB * NC * T0 * sizeof(float);   // 20.4 MB
    const bool useD = ws_size >= D_BYTES;

    zeroK<<<(out_size + 255) / 256, 256, 0, stream>>>(out, out_size);
    if (useD) {
        dim3 dg((T0 + 255) / 256, NB * NC);
        diffK<<<dg, 256, 0, stream>>>(X, Dws);
        kernA<true><<<A_TOTAL_BLOCKS, 256, 0, stream>>>(X, Dws, Wt, idx, out);
        kernP<true><<<P_BLOCKS, 256, 0, stream>>>(X, Dws, Wt, idx, out);
    } else {
        kernA<false><<<A_TOTAL_BLOCKS, 256, 0, stream>>>(X, Dws, Wt, idx, out);
        kernP<false><<<P_BLOCKS, 256, 0, stream>>>(X, Dws, Wt, idx, out);
    }
}

// Round 11
// 1604.552 us; speedup vs baseline: 1.1040x; 1.1040x over previous
//
#include <hip/hip_runtime.h>

typedef float F2 __attribute__((ext_vector_type(2)));

#define NB 4
#define NC 17
#define T0 75000
#define NH 32
#define NK 8

// ---------------- diff precompute: D[b][c][t] = X[t+1]-X[t], D[T0-1]=0 ----------------
__global__ void diffK(const float* __restrict__ X, float* __restrict__ D) {
    int t = blockIdx.x * 256 + threadIdx.x;
    int row = blockIdx.y;
    if (t < T0) {
        size_t o = (size_t)row * T0 + t;
        D[o] = (t < T0 - 1) ? (X[o + 1] - X[o]) : 0.f;
    }
}

// pack k into low 3 mantissa bits; max/min trees then carry the arg-index.
// min ties resolve to smallest k (matches reference); max ties to largest
// (mismatch only on exact float ties; empirically within threshold since R2).
__device__ __forceinline__ float packK(float z, int k) {
    unsigned u = (__float_as_uint(z) & 0xFFFFFFF8u) | (unsigned)k;
    return __uint_as_float(u);
}
__device__ __forceinline__ float max8(const float* p) {
    return fmaxf(fmaxf(fmaxf(p[0], p[1]), fmaxf(p[2], p[3])),
                 fmaxf(fmaxf(p[4], p[5]), fmaxf(p[6], p[7])));
}
__device__ __forceinline__ float min8(const float* p) {
    return fminf(fminf(fminf(p[0], p[1]), fminf(p[2], p[3])),
                 fminf(fminf(p[4], p[5]), fminf(p[6], p[7])));
}

// ---------------- kernel A: di 0..5 (d = 1..32), LDS-tiled ----------------
constexpr int TS = 1024;
constexpr int A_TILES = 74;
constexpr int A_BLOCKS_PER_G = 128 * A_TILES;   // 9472
constexpr int A_GROUPS = 12;
constexpr int A_TOTAL_BLOCKS = A_GROUPS * A_BLOCKS_PER_G;  // 113664

template <bool USE_D>
__global__ __launch_bounds__(256) void kernA(const float* __restrict__ X,
                                             const float* __restrict__ Dws,
                                             const float* __restrict__ Wt,
                                             const int* __restrict__ idx,
                                             float* __restrict__ out) {
    __shared__ float Sbuf[TS + 8 * 32 + 2];
    __shared__ float red[4][16];

    const int tid = threadIdx.x;
    const int bid = blockIdx.x;
    const int ga = bid / A_BLOCKS_PER_G;
    const int rem = bid - ga * A_BLOCKS_PER_G;
    const int b = rem & 3;                       // XCD locality: b fastest
    const int z = rem >> 2;
    const int h = z & 31;
    const int tile = z >> 5;
    const int di = ga >> 1, diff = ga & 1;
    const int d = 1 << di;
    const int T = T0 - diff;
    const int t0 = tile * TS;
    const int span = TS + 8 * d;
    const int g0 = t0 - 4 * d;                   // even

    const int* ip = idx + (ga * NH + h) * 8;
    int offs[8];
#pragma unroll
    for (int i = 0; i < 8; ++i)
        offs[i] = __builtin_amdgcn_readfirstlane((b * NC + ip[i]) * T0);

    if (USE_D) {
        const float* base = diff ? Dws : X;
        for (int e = tid * 2; e < span; e += 512) {
            int u = g0 + e;
            F2 s = {0.f, 0.f};
            if (u >= 0 && u + 1 < T0) {
#pragma unroll
                for (int i = 0; i < 8; ++i) s += *(const F2*)(base + offs[i] + u);
            } else {
#pragma unroll
                for (int c = 0; c < 2; ++c) {
                    int uc = u + c;
                    float sc = 0.f;
                    if (uc >= 0 && uc < T0) {
#pragma unroll
                        for (int i = 0; i < 8; ++i) sc += base[offs[i] + uc];
                    }
                    s[c] = sc;
                }
            }
            if (e + 1 < span) *(F2*)(Sbuf + e) = s;
            else Sbuf[e] = s.x;
        }
    } else {
        for (int ls = tid; ls < span; ls += 256) {
            int u = g0 + ls;
            float s = 0.f;
            if (diff) {
                if (u >= 0 && u < T0 - 1) {
#pragma unroll
                    for (int i = 0; i < 8; ++i) s += X[offs[i] + u + 1] - X[offs[i] + u];
                }
            } else {
                if (u >= 0 && u < T0) {
#pragma unroll
                    for (int i = 0; i < 8; ++i) s += X[offs[i] + u];
                }
            }
            Sbuf[ls] = s;
        }
    }
    __syncthreads();

    const float* wp = Wt + (ga * (NK * NH) + h * NK) * 9;
    float w[72];
#pragma unroll
    for (int i = 0; i < 72; ++i) w[i] = wp[i];   // block-uniform -> SGPRs

    float accM[8];
#pragma unroll
    for (int k = 0; k < 8; ++k) accM[k] = 0.f;
    unsigned cnt = 0;                            // 8 x 4-bit min-count fields (<=4)

#pragma unroll
    for (int it = 0; it < 4; ++it) {
        int pos = tid + it * 256;
        int t = t0 + pos;
        if (t < T) {
            float zv[8];
#pragma unroll
            for (int k = 0; k < 8; ++k) zv[k] = 0.f;
#pragma unroll
            for (int j = 0; j < 9; ++j) {
                float g = Sbuf[pos + j * d];
#pragma unroll
                for (int k = 0; k < 8; ++k) zv[k] = fmaf(w[k * 9 + j], g, zv[k]);
            }
            float p[8];
#pragma unroll
            for (int k = 0; k < 8; ++k) p[k] = packK(zv[k], k);
            float best = max8(p), worst = min8(p);
            int biK = __float_as_uint(best) & 7;
            int wiK = __float_as_uint(worst) & 7;
#pragma unroll
            for (int k = 0; k < 8; ++k) accM[k] += (k == biK) ? best : 0.f;
            cnt += 1u << (wiK << 2);
        }
    }

    float accC[8];
#pragma unroll
    for (int k = 0; k < 8; ++k) accC[k] = (float)((cnt >> (k * 4)) & 15u);

#pragma unroll
    for (int k = 0; k < 8; ++k) {
#pragma unroll
        for (int sh = 1; sh < 64; sh <<= 1) {
            accM[k] += __shfl_xor(accM[k], sh, 64);
            accC[k] += __shfl_xor(accC[k], sh, 64);
        }
    }
    int wv = tid >> 6, lane = tid & 63;
    if (lane == 0) {
#pragma unroll
        for (int k = 0; k < 8; ++k) { red[wv][k] = accM[k]; red[wv][8 + k] = accC[k]; }
    }
    __syncthreads();
    if (tid < 16) {
        float v = red[0][tid] + red[1][tid] + red[2][tid] + red[3][tid];
        int which = tid >> 3;
        int k = tid & 7;
        int o = ga * 2 + which;
        atomicAdd(&out[(size_t)b * 14336 + (o * NH + h) * NK + k], v);
    }
}

// ---------------- kernel P: di 6..13 phase-space LDS tiles, register epilogue ----------------
// position t = r + q*d; y_r[q] = S[r + q*d] -> contiguous 9-tap conv over q.
// Block = (b, h, group, r-tile of 64, q-tile of 16); rows qi=0..23 staged
// (qglob = qb-4+qi); out-of-range rows stage 0 == reference zero padding.
constexpr int QT = 16;

struct PG { int base, rtiles, qtiles, di, diff; };
constexpr PG PGS[16] = {
    {0,      1,  74,  6, 0}, {9472,   1,  74,  6, 1},
    {18944,  2,  37,  7, 0}, {28416,  2,  37,  7, 1},
    {37888,  4,  19,  8, 0}, {47616,  4,  19,  8, 1},
    {57344,  8,  10,  9, 0}, {67584,  8,  10,  9, 1},
    {77824, 16,   5, 10, 0}, {88064, 16,   5, 10, 1},
    {98304, 32,   3, 11, 0}, {110592,32,   3, 11, 1},
    {122880,64,   2, 12, 0}, {139264,64,   2, 12, 1},
    {155648,128,  1, 13, 0}, {172032,128,  1, 13, 1},
};
constexpr int P_BLOCKS = 188416;

template <bool USE_D>
__device__ __forceinline__ float gatherF(const float* __restrict__ base,
                                         const int* offs, int u, int T, int diffF) {
    float s = 0.f;
    if (u >= 0 && u < T) {
        if (!USE_D && diffF) {
            F2 acc = {0.f, 0.f};
#pragma unroll
            for (int i = 0; i < 8; ++i) {
                F2 t = {base[offs[i] + u], base[offs[i] + u + 1]};
                acc += t;
            }
            s = acc.y - acc.x;
        } else {
            float a0 = base[offs[0] + u], a1 = base[offs[1] + u];
            float a2 = base[offs[2] + u], a3 = base[offs[3] + u];
            float a4 = base[offs[4] + u], a5 = base[offs[5] + u];
            float a6 = base[offs[6] + u], a7 = base[offs[7] + u];
            s = ((a0 + a1) + (a2 + a3)) + ((a4 + a5) + (a6 + a7));
        }
    }
    return s;
}

template <bool USE_D>
__global__ __launch_bounds__(256) void kernP(const float* __restrict__ X,
                                             const float* __restrict__ Dws,
                                             const float* __restrict__ Wt,
                                             const int* __restrict__ idx,
                                             float* __restrict__ out) {
    __shared__ float Sld[24 * 64];               // 6 KB phase tile
    __shared__ float red[4][16];

    const int tid = threadIdx.x;
    const int bid = blockIdx.x;

    int di = 6, diff = 0, beta = 0, lrt = 0;
#pragma unroll
    for (int g = 0; g < 16; ++g) {
        const int sz = 128 * PGS[g].rtiles * PGS[g].qtiles;
        if (bid >= PGS[g].base && bid < PGS[g].base + sz) {
            beta = bid - PGS[g].base;
            di = PGS[g].di; diff = PGS[g].diff; lrt = PGS[g].di - 6;
        }
    }
    const int b = beta & 3;                      // XCD locality
    const int z = beta >> 2;
    const int h = z & 31;
    const int rq = z >> 5;
    const int rtile = rq & ((1 << lrt) - 1);
    const int qtile = rq >> lrt;

    const int d = 1 << di;
    const int T = T0 - diff;
    const int ga = di * 2 + diff;
    const int r0 = rtile * 64;
    const int qb = qtile * QT;

    const int* ip = idx + (ga * NH + h) * 8;
    int offs[8];
#pragma unroll
    for (int i = 0; i < 8; ++i)
        offs[i] = __builtin_amdgcn_readfirstlane((b * NC + ip[i]) * T0);

    const float* base = (USE_D && diff) ? Dws : X;

    // stage 24x64 tile: element e = qi*64+ln, t = r0+ln + (qb-4+qi)*d
#pragma unroll
    for (int it = 0; it < 6; ++it) {
        const int e = tid + it * 256;
        const int qi = e >> 6, ln = e & 63;
        const int t = r0 + ln + (qb - 4 + qi) * d;
        Sld[e] = gatherF<USE_D>(base, offs, t, T, diff);
    }
    __syncthreads();

    const float* wp = Wt + (ga * (NK * NH) + h * NK) * 9;
    float w[72];
#pragma unroll
    for (int i = 0; i < 72; ++i) w[i] = wp[i];   // block-uniform -> SGPRs

    const int r = tid & 63;
    const int qs = tid >> 6;                     // 4 waves over q

    float accM[8];
#pragma unroll
    for (int k = 0; k < 8; ++k) accM[k] = 0.f;
    unsigned cnt = 0;                            // 8 x 4-bit fields (<=4/thread)

#pragma unroll
    for (int it = 0; it < 4; ++it) {
        const int qloc = qs + it * 4;            // 0..15
        const int t = r0 + r + (qb + qloc) * d;
        if (t < T) {
            float zv[8];
#pragma unroll
            for (int k = 0; k < 8; ++k) zv[k] = 0.f;
#pragma unroll
            for (int j = 0; j < 9; ++j) {
                float g = Sld[(qloc + j) * 64 + r];
#pragma unroll
                for (int k = 0; k < 8; ++k) zv[k] = fmaf(w[k * 9 + j], g, zv[k]);
            }
            float p[8];
#pragma unroll
            for (int k = 0; k < 8; ++k) p[k] = packK(zv[k], k);
            float best = max8(p), worst = min8(p);
            int biK = __float_as_uint(best) & 7;
            int wiK = __float_as_uint(worst) & 7;
#pragma unroll
            for (int k = 0; k < 8; ++k) accM[k] += (k == biK) ? best : 0.f;
            cnt += 1u << (wiK << 2);
        }
    }

    float accC[8];
#pragma unroll
    for (int k = 0; k < 8; ++k) accC[k] = (float)((cnt >> (k * 4)) & 15u);

#pragma unroll
    for (int k = 0; k < 8; ++k) {
#pragma unroll
        for (int sh = 1; sh < 64; sh <<= 1) {
            accM[k] += __shfl_xor(accM[k], sh, 64);
            accC[k] += __shfl_xor(accC[k], sh, 64);
        }
    }
    int wv = tid >> 6, lane = tid & 63;
    if (lane == 0) {
#pragma unroll
        for (int k = 0; k < 8; ++k) { red[wv][k] = accM[k]; red[wv][8 + k] = accC[k]; }
    }
    __syncthreads();
    if (tid < 16) {
        float v = red[0][tid] + red[1][tid] + red[2][tid] + red[3][tid];
        int which = tid >> 3;
        int k = tid & 7;
        int o = ga * 2 + which;
        atomicAdd(&out[(size_t)b * 14336 + (o * NH + h) * NK + k], v);
    }
}

__global__ void zeroK(float* __restrict__ out, int n) {
    int i = blockIdx.x * 256 + threadIdx.x;
    if (i < n) out[i] = 0.f;
}

extern "C" void kernel_launch(void* const* d_in, const int* in_sizes, int n_in,
                              void* d_out, int out_size, void* d_ws, size_t ws_size,
                              hipStream_t stream) {
    const float* X  = (const float*)d_in[0];
    const float* Wt = (const float*)d_in[1];
    const int*  idx = (const int*)d_in[2];
    float* out = (float*)d_out;
    float* Dws = (float*)d_ws;

    const size_t D_BYTES = (size_t)NB * NC * T0 * sizeof(float);   // 20.4 MB
    const bool useD = ws_size >= D_BYTES;

    zeroK<<<(out_size + 255) / 256, 256, 0, stream>>>(out, out_size);
    if (useD) {
        dim3 dg((T0 + 255) / 256, NB * NC);
        diffK<<<dg, 256, 0, stream>>>(X, Dws);
        kernA<true><<<A_TOTAL_BLOCKS, 256, 0, stream>>>(X, Dws, Wt, idx, out);
        kernP<true><<<P_BLOCKS, 256, 0, stream>>>(X, Dws, Wt, idx, out);
    } else {
        kernA<false><<<A_TOTAL_BLOCKS, 256, 0, stream>>>(X, Dws, Wt, idx, out);
        kernP<false><<<P_BLOCKS, 256, 0, stream>>>(X, Dws, Wt, idx, out);
    }
}

// Round 12
// 1336.380 us; speedup vs baseline: 1.3255x; 1.2007x over previous
//
#include <hip/hip_runtime.h>

typedef float F2 __attribute__((ext_vector_type(2)));

#define NB 4
#define NC 17
#define T0 75000
#define NH 32
#define NK 8

// ---------------- diff precompute: D[b][c][t] = X[t+1]-X[t], D[T0-1]=0 ----------------
__global__ void diffK(const float* __restrict__ X, float* __restrict__ D) {
    int t = blockIdx.x * 256 + threadIdx.x;
    int row = blockIdx.y;
    if (t < T0) {
        size_t o = (size_t)row * T0 + t;
        D[o] = (t < T0 - 1) ? (X[o + 1] - X[o]) : 0.f;
    }
}

// pack k into low 3 mantissa bits; max/min trees carry the arg-index
__device__ __forceinline__ float packK(float z, int k) {
    unsigned u = (__float_as_uint(z) & 0xFFFFFFF8u) | (unsigned)k;
    return __uint_as_float(u);
}
__device__ __forceinline__ float max8(const float* p) {
    return fmaxf(fmaxf(fmaxf(p[0], p[1]), fmaxf(p[2], p[3])),
                 fmaxf(fmaxf(p[4], p[5]), fmaxf(p[6], p[7])));
}
__device__ __forceinline__ float min8(const float* p) {
    return fminf(fminf(fminf(p[0], p[1]), fminf(p[2], p[3])),
                 fminf(fminf(p[4], p[5]), fminf(p[6], p[7])));
}

// ---------------- kernel A: di 0..5 (d = 1..32), LDS-tiled (R11 champion) ----------------
constexpr int TS = 1024;
constexpr int A_TILES = 74;
constexpr int A_BLOCKS_PER_G = 128 * A_TILES;   // 9472
constexpr int A_GROUPS = 12;
constexpr int A_TOTAL_BLOCKS = A_GROUPS * A_BLOCKS_PER_G;  // 113664

template <bool USE_D>
__global__ __launch_bounds__(256) void kernA(const float* __restrict__ X,
                                             const float* __restrict__ Dws,
                                             const float* __restrict__ Wt,
                                             const int* __restrict__ idx,
                                             float* __restrict__ out) {
    __shared__ float Sbuf[TS + 8 * 32 + 2];
    __shared__ float red[4][16];

    const int tid = threadIdx.x;
    const int bid = blockIdx.x;
    const int ga = bid / A_BLOCKS_PER_G;
    const int rem = bid - ga * A_BLOCKS_PER_G;
    const int b = rem & 3;                       // XCD locality: b fastest
    const int z = rem >> 2;
    const int h = z & 31;
    const int tile = z >> 5;
    const int di = ga >> 1, diff = ga & 1;
    const int d = 1 << di;
    const int T = T0 - diff;
    const int t0 = tile * TS;
    const int span = TS + 8 * d;
    const int g0 = t0 - 4 * d;                   // even

    const int* ip = idx + (ga * NH + h) * 8;
    int offs[8];
#pragma unroll
    for (int i = 0; i < 8; ++i)
        offs[i] = __builtin_amdgcn_readfirstlane((b * NC + ip[i]) * T0);

    if (USE_D) {
        const float* base = diff ? Dws : X;
        for (int e = tid * 2; e < span; e += 512) {
            int u = g0 + e;
            F2 s = {0.f, 0.f};
            if (u >= 0 && u + 1 < T0) {
#pragma unroll
                for (int i = 0; i < 8; ++i) s += *(const F2*)(base + offs[i] + u);
            } else {
#pragma unroll
                for (int c = 0; c < 2; ++c) {
                    int uc = u + c;
                    float sc = 0.f;
                    if (uc >= 0 && uc < T0) {
#pragma unroll
                        for (int i = 0; i < 8; ++i) sc += base[offs[i] + uc];
                    }
                    s[c] = sc;
                }
            }
            if (e + 1 < span) *(F2*)(Sbuf + e) = s;
            else Sbuf[e] = s.x;
        }
    } else {
        for (int ls = tid; ls < span; ls += 256) {
            int u = g0 + ls;
            float s = 0.f;
            if (diff) {
                if (u >= 0 && u < T0 - 1) {
#pragma unroll
                    for (int i = 0; i < 8; ++i) s += X[offs[i] + u + 1] - X[offs[i] + u];
                }
            } else {
                if (u >= 0 && u < T0) {
#pragma unroll
                    for (int i = 0; i < 8; ++i) s += X[offs[i] + u];
                }
            }
            Sbuf[ls] = s;
        }
    }
    __syncthreads();

    const float* wp = Wt + (ga * (NK * NH) + h * NK) * 9;
    float w[72];
#pragma unroll
    for (int i = 0; i < 72; ++i) w[i] = wp[i];   // block-uniform -> SGPRs

    float accM[8];
#pragma unroll
    for (int k = 0; k < 8; ++k) accM[k] = 0.f;
    unsigned cnt = 0;                            // 8 x 4-bit min-count fields (<=4)

#pragma unroll
    for (int it = 0; it < 4; ++it) {
        int pos = tid + it * 256;
        int t = t0 + pos;
        if (t < T) {
            float zv[8];
#pragma unroll
            for (int k = 0; k < 8; ++k) zv[k] = 0.f;
#pragma unroll
            for (int j = 0; j < 9; ++j) {
                float g = Sbuf[pos + j * d];
#pragma unroll
                for (int k = 0; k < 8; ++k) zv[k] = fmaf(w[k * 9 + j], g, zv[k]);
            }
            float p[8];
#pragma unroll
            for (int k = 0; k < 8; ++k) p[k] = packK(zv[k], k);
            float best = max8(p), worst = min8(p);
            int biK = __float_as_uint(best) & 7;
            int wiK = __float_as_uint(worst) & 7;
#pragma unroll
            for (int k = 0; k < 8; ++k) accM[k] += (k == biK) ? best : 0.f;
            cnt += 1u << (wiK << 2);
        }
    }

    float accC[8];
#pragma unroll
    for (int k = 0; k < 8; ++k) accC[k] = (float)((cnt >> (k * 4)) & 15u);

#pragma unroll
    for (int k = 0; k < 8; ++k) {
#pragma unroll
        for (int sh = 1; sh < 64; sh <<= 1) {
            accM[k] += __shfl_xor(accM[k], sh, 64);
            accC[k] += __shfl_xor(accC[k], sh, 64);
        }
    }
    int wv = tid >> 6, lane = tid & 63;
    if (lane == 0) {
#pragma unroll
        for (int k = 0; k < 8; ++k) { red[wv][k] = accM[k]; red[wv][8 + k] = accC[k]; }
    }
    __syncthreads();
    if (tid < 16) {
        float v = red[0][tid] + red[1][tid] + red[2][tid] + red[3][tid];
        int which = tid >> 3;
        int k = tid & 7;
        int o = ga * 2 + which;
        atomicAdd(&out[(size_t)b * 14336 + (o * NH + h) * NK + k], v);
    }
}

// ---------------- kernel B2: di 6..13, phase-PAIR F2 register ring ----------------
// Thread owns phases (r, r+1), r = 2p, one q-chain of <=60. Ring slot m holds
// F2 {S[t], S[t+1]} at t = r + (q0+m-4)*d. One dwordx2 per channel serves both
// positions. segs2 = (d/2)*ceil(Q/60), all multiples of 64 -> combo wave-uniform.
struct BG2 { int base, segs2, di, diff; };       // base in blocks (blocks = 128*segs2/256)
constexpr BG2 BGS2[16] = {
    {0,     640,  6, 0}, {320,   640,  6, 1},
    {640,   640,  7, 0}, {960,   640,  7, 1},
    {1280,  640,  8, 0}, {1600,  640,  8, 1},
    {1920,  768,  9, 0}, {2304,  768,  9, 1},
    {2688, 1024, 10, 0}, {3200, 1024, 10, 1},
    {3712, 1024, 11, 0}, {4224, 1024, 11, 1},
    {4736, 2048, 12, 0}, {5760, 2048, 12, 1},
    {6784, 4096, 13, 0}, {8832, 4096, 13, 1},
};
constexpr int B2_BLOCKS = 10880;

// F2 gather {S[u], S[u+1]} with zero outside [0, T0). For USE_D diff rows,
// D[T0-1]=0 already encodes the logical zero-pad at T-1.
template <bool USE_D>
__device__ __forceinline__ F2 gather2(const float* __restrict__ base,
                                      const int* offs, int u, int diffF) {
    F2 s = {0.f, 0.f};
    if (u >= 0 && u + 1 < T0) {                  // fast path: aligned dwordx2
        if (!USE_D && diffF) {
            float m0 = 0.f, m1 = 0.f, m2 = 0.f;
#pragma unroll
            for (int i = 0; i < 8; ++i) {
                m0 += base[offs[i] + u];
                m1 += base[offs[i] + u + 1];
                m2 += (u + 2 < T0) ? base[offs[i] + u + 2] : base[offs[i] + u + 1];
            }
            s.x = m1 - m0;
            s.y = (u + 2 < T0) ? (m2 - m1) : 0.f;
        } else {
#pragma unroll
            for (int i = 0; i < 8; ++i) s += *(const F2*)(base + offs[i] + u);
        }
    } else if (u + 1 >= 0 && u < T0) {           // edge: per-component
#pragma unroll
        for (int c = 0; c < 2; ++c) {
            int uc = u + c;
            float sc = 0.f;
            if (uc >= 0 && uc < T0) {
                if (!USE_D && diffF) {
                    if (uc < T0 - 1) {
#pragma unroll
                        for (int i = 0; i < 8; ++i)
                            sc += base[offs[i] + uc + 1] - base[offs[i] + uc];
                    }
                } else {
#pragma unroll
                    for (int i = 0; i < 8; ++i) sc += base[offs[i] + uc];
                }
            }
            s[c] = sc;
        }
    }
    return s;
}

template <bool USE_D>
__global__ __launch_bounds__(256, 4) void kernB2(const float* __restrict__ X,
                                                 const float* __restrict__ Dws,
                                                 const float* __restrict__ Wt,
                                                 const int* __restrict__ idx,
                                                 float* __restrict__ out) {
    const int tid = threadIdx.x;
    const int bid = blockIdx.x;

    int di = 6, diff = 0, gig = 0, combo = 0, sg = 0;
#pragma unroll
    for (int g = 0; g < 16; ++g) {
        const int s2 = BGS2[g].segs2;
        const int nb = s2 / 2;                   // blocks per combo-pair... (128*s2/256)
        if (bid >= BGS2[g].base && bid < BGS2[g].base + 128 * s2 / 256) {
            gig = (bid - BGS2[g].base) * 256 + tid;
            combo = gig / s2;                    // compile-time magic div
            sg = gig - combo * s2;
            di = BGS2[g].di; diff = BGS2[g].diff;
        }
        (void)nb;
    }
    combo = __builtin_amdgcn_readfirstlane(combo);   // wave-uniform (segs2 % 64 == 0)
    di    = __builtin_amdgcn_readfirstlane(di);
    diff  = __builtin_amdgcn_readfirstlane(diff);

    const int d = 1 << di;
    const int T = T0 - diff;
    const int Q = (T + d - 1) >> di;
    const int ga = di * 2 + diff;
    const int b = combo & 3;                     // XCD locality: b fastest
    const int h = combo >> 2;

    const int p = sg & ((d >> 1) - 1);
    const int q0 = (sg >> (di - 1)) * 60;        // per-lane ok
    const int r = 2 * p;

    const int* ip = idx + (ga * NH + h) * 8;
    int offs[8];
#pragma unroll
    for (int i = 0; i < 8; ++i)
        offs[i] = __builtin_amdgcn_readfirstlane((b * NC + ip[i]) * T0);

    const float* wp = Wt + (ga * (NK * NH) + h * NK) * 9;
    float w[72];
#pragma unroll
    for (int i = 0; i < 72; ++i) w[i] = wp[i];   // wave-uniform -> SGPRs

    const float* base = (USE_D && diff) ? Dws : X;

    float accM[8];
#pragma unroll
    for (int k = 0; k < 8; ++k) accM[k] = 0.f;
    unsigned long long cnt = 0;                  // 8 x 8-bit fields (<=120)

    const int t0 = r + q0 * d;
    F2 buf[12];                                  // slot m: t = t0 + (m-4)*d
    {
        int u = t0 - 4 * d;
#pragma unroll
        for (int m = 0; m < 12; ++m) { buf[m] = gather2<USE_D>(base, offs, u, diff); u += d; }
    }

    for (int outer = 0; outer < 5; ++outer) {
        if (q0 + outer * 12 >= Q) break;
        const int tb = t0 + outer * 12 * d;
#pragma unroll
        for (int ii = 0; ii < 12; ++ii) {
            const int t = tb + ii * d;           // position x: t, position y: t+1
            F2 Z[8];
#pragma unroll
            for (int k = 0; k < 8; ++k) Z[k] = (F2){0.f, 0.f};
#pragma unroll
            for (int j = 0; j < 9; ++j) {
                F2 g = buf[(ii + j) % 12];
#pragma unroll
                for (int k = 0; k < 8; ++k) {
                    F2 wv = {w[k * 9 + j], w[k * 9 + j]};
                    Z[k] = __builtin_elementwise_fma(wv, g, Z[k]);
                }
            }
            // epilogue position x
            if (t < T) {
                float px[8];
#pragma unroll
                for (int k = 0; k < 8; ++k) px[k] = packK(Z[k].x, k);
                float best = max8(px), worst = min8(px);
                int biK = __float_as_uint(best) & 7;
                int wiK = __float_as_uint(worst) & 7;
#pragma unroll
                for (int k = 0; k < 8; ++k) accM[k] += (k == biK) ? best : 0.f;
                cnt += 1ull << (wiK << 3);
            }
            // epilogue position y
            if (t + 1 < T) {
                float py[8];
#pragma unroll
                for (int k = 0; k < 8; ++k) py[k] = packK(Z[k].y, k);
                float best = max8(py), worst = min8(py);
                int biK = __float_as_uint(best) & 7;
                int wiK = __float_as_uint(worst) & 7;
#pragma unroll
                for (int k = 0; k < 8; ++k) accM[k] += (k == biK) ? best : 0.f;
                cnt += 1ull << (wiK << 3);
            }
            buf[ii] = gather2<USE_D>(base, offs, t + 8 * d, diff);
        }
    }

    float accC[8];
#pragma unroll
    for (int k = 0; k < 8; ++k) accC[k] = (float)((unsigned)(cnt >> (k * 8)) & 255u);

    // per-wave butterfly (combo wave-uniform; block may straddle combos)
#pragma unroll
    for (int k = 0; k < 8; ++k) {
#pragma unroll
        for (int sh = 1; sh < 64; sh <<= 1) {
            accM[k] += __shfl_xor(accM[k], sh, 64);
            accC[k] += __shfl_xor(accC[k], sh, 64);
        }
    }
    if ((tid & 63) == 0) {
        size_t bb = (size_t)b * 14336;
        int o = ga * 2;
#pragma unroll
        for (int k = 0; k < 8; ++k) {
            atomicAdd(&out[bb + (o * NH + h) * NK + k],       accM[k]);
            atomicAdd(&out[bb + ((o + 1) * NH + h) * NK + k], accC[k]);
        }
    }
}

__global__ void zeroK(float* __restrict__ out, int n) {
    int i = blockIdx.x * 256 + threadIdx.x;
    if (i < n) out[i] = 0.f;
}

extern "C" void kernel_launch(void* const* d_in, const int* in_sizes, int n_in,
                              void* d_out, int out_size, void* d_ws, size_t ws_size,
                              hipStream_t stream) {
    const float* X  = (const float*)d_in[0];
    const float* Wt = (const float*)d_in[1];
    const int*  idx = (const int*)d_in[2];
    float* out = (float*)d_out;
    float* Dws = (float*)d_ws;

    const size_t D_BYTES = (size_t)NB * NC * T0 * sizeof(float);   // 20.4 MB
    const bool useD = ws_size >= D_BYTES;

    zeroK<<<(out_size + 255) / 256, 256, 0, stream>>>(out, out_size);
    if (useD) {
        dim3 dg((T0 + 255) / 256, NB * NC);
        diffK<<<dg, 256, 0, stream>>>(X, Dws);
        kernA<true><<<A_TOTAL_BLOCKS, 256, 0, stream>>>(X, Dws, Wt, idx, out);
        kernB2<true><<<B2_BLOCKS, 256, 0, stream>>>(X, Dws, Wt, idx, out);
    } else {
        kernA<false><<<A_TOTAL_BLOCKS, 256, 0, stream>>>(X, Dws, Wt, idx, out);
        kernB2<false><<<B2_BLOCKS, 256, 0, stream>>>(X, Dws, Wt, idx, out);
    }
}